// Round 5
// baseline (1768.690 us; speedup 1.0000x reference)
//
#include <hip/hip_runtime.h>

// GRU: B=128, T=2048, H=128.
// Kernel 1 (gru_proj): xz/xr/xh = x @ W^T + b via bf16 MFMA 16x16x32.
//   xz,xr packed as 2x bf16 into d_out words (consumed then overwritten by h),
//   xh as bf16 into d_ws.
// Kernel 2 (gru_rec4): 1 batch/block x 128 blocks, 4 waves x 32 units.
//   Broadcast-A MFMA matvecs (k-reduce inside MFMA). Phase A: r gate only ->
//   fastest path to rh exchange. Phase B: z (on register-resident h frags,
//   overlaps rh ds_read latency) + h~ + update. 2 lgkm-only barriers/step;
//   2-deep global prefetch + fire-and-forget h stores (vmcnt never drained).
//   All bf16 packing is RNE via (__bf16) casts (no cvt_pk truncation risk).

#define T_LEN 2048
#define H_DIM 128

typedef __attribute__((ext_vector_type(8))) __bf16 bf16x8;
typedef __attribute__((ext_vector_type(4))) float f32x4;

// raw barrier: drains LDS ops (cross-wave visibility) but NOT vmcnt. [m201]
#define BARRIER() asm volatile("s_waitcnt lgkmcnt(0)\n\ts_barrier" ::: "memory")

__device__ __forceinline__ unsigned short f2bf_bits(float f){
  __bf16 b = (__bf16)f;                     // fptrunc, RNE
  return __builtin_bit_cast(unsigned short, b);
}
__device__ __forceinline__ float bf2f(unsigned short s){
  unsigned int u = ((unsigned int)s) << 16;
  return __builtin_bit_cast(float, u);
}
__device__ __forceinline__ unsigned int pack_bf16_rne(float lo, float hi){
  return (unsigned int)f2bf_bits(lo) | (((unsigned int)f2bf_bits(hi)) << 16);
}
__device__ __forceinline__ float sigm(float x){
  return 1.0f / (1.0f + exp2f(-1.4426950408889634f * x));
}
__device__ __forceinline__ float tanh_fast(float x){
  float e = exp2f(2.8853900817779268f * x);   // e^(2x); inf-safe
  return 1.0f - 2.0f / (e + 1.0f);
}
// lane <- lane^1 value (quad_perm [1,0,3,2] = 0xB1); run in ALL lanes
__device__ __forceinline__ float dpp_xor1(float x){
  int r = __builtin_amdgcn_update_dpp(0, __builtin_bit_cast(int, x),
                                      0xB1, 0xF, 0xF, true);
  return __builtin_bit_cast(float, r);
}

// ---------------- projection GEMM (unchanged, verified) ----------------

__device__ __forceinline__ void stage_mat128(const float* __restrict__ src,
                                             __bf16 (*dst)[136], int tid){
  #pragma unroll
  for (int rep = 0; rep < 8; ++rep){
    int fi = rep * 2048 + tid * 4;
    float4 v = *reinterpret_cast<const float4*>(src + fi);
    int m = fi >> 7;
    int k = fi & 127;
    unsigned long long pk =
        (unsigned long long)f2bf_bits(v.x)
      | ((unsigned long long)f2bf_bits(v.y) << 16)
      | ((unsigned long long)f2bf_bits(v.z) << 32)
      | ((unsigned long long)f2bf_bits(v.w) << 48);
    *reinterpret_cast<unsigned long long*>(&dst[m][k]) = pk;
  }
}

__global__ __launch_bounds__(512, 2) void gru_proj(
    const float* __restrict__ x,
    const float* __restrict__ Wz, const float* __restrict__ Wr, const float* __restrict__ Wh,
    const float* __restrict__ bz, const float* __restrict__ br, const float* __restrict__ bh,
    unsigned int* __restrict__ out_zr, unsigned short* __restrict__ out_h)
{
  __shared__ __bf16 xs[128][136];
  __shared__ __bf16 wsh[3][128][136];

  const int tid = threadIdx.x;
  const long Mbase = (long)blockIdx.x * 128;

  stage_mat128(x + Mbase * H_DIM, xs, tid);
  stage_mat128(Wz, wsh[0], tid);
  stage_mat128(Wr, wsh[1], tid);
  stage_mat128(Wh, wsh[2], tid);
  __syncthreads();

  const int w  = tid >> 6, l = tid & 63;
  const int ml = l & 15;
  const int kl = (l >> 4) * 8;
  const int n  = w * 16 + ml;

  bf16x8 bfr[3][4];
  #pragma unroll
  for (int g = 0; g < 3; ++g)
    #pragma unroll
    for (int kk = 0; kk < 4; ++kk)
      bfr[g][kk] = *reinterpret_cast<const bf16x8*>(&wsh[g][n][kk * 32 + kl]);

  const float bzv = bz[n], brv = br[n], bhv = bh[n];

  f32x4 acc[8][3];
  #pragma unroll
  for (int mt = 0; mt < 8; ++mt)
    #pragma unroll
    for (int g = 0; g < 3; ++g)
      acc[mt][g] = (f32x4){0.f, 0.f, 0.f, 0.f};

  #pragma unroll
  for (int mt = 0; mt < 8; ++mt){
    #pragma unroll
    for (int kk = 0; kk < 4; ++kk){
      bf16x8 a = *reinterpret_cast<const bf16x8*>(&xs[mt * 16 + ml][kk * 32 + kl]);
      acc[mt][0] = __builtin_amdgcn_mfma_f32_16x16x32_bf16(a, bfr[0][kk], acc[mt][0], 0, 0, 0);
      acc[mt][1] = __builtin_amdgcn_mfma_f32_16x16x32_bf16(a, bfr[1][kk], acc[mt][1], 0, 0, 0);
      acc[mt][2] = __builtin_amdgcn_mfma_f32_16x16x32_bf16(a, bfr[2][kk], acc[mt][2], 0, 0, 0);
    }
  }

  #pragma unroll
  for (int mt = 0; mt < 8; ++mt){
    #pragma unroll
    for (int p = 0; p < 4; ++p){
      long row = Mbase + mt * 16 + (l >> 4) * 4 + p;
      float vz = acc[mt][0][p] + bzv;
      float vr = acc[mt][1][p] + brv;
      float vh = acc[mt][2][p] + bhv;
      unsigned int word = (unsigned int)f2bf_bits(vz)
                        | (((unsigned int)f2bf_bits(vr)) << 16);
      out_zr[row * H_DIM + n] = word;
      out_h [row * H_DIM + n] = f2bf_bits(vh);
    }
  }
}

// ---------------- recurrence: broadcast-A MFMA, 4 waves, 1 batch/block ------

__device__ __forceinline__ bf16x8 ld_u_frag(const float* p){
  float4 a = *reinterpret_cast<const float4*>(p);
  float4 b = *reinterpret_cast<const float4*>(p + 4);
  bf16x8 r;
  r[0]=(__bf16)a.x; r[1]=(__bf16)a.y; r[2]=(__bf16)a.z; r[3]=(__bf16)a.w;
  r[4]=(__bf16)b.x; r[5]=(__bf16)b.y; r[6]=(__bf16)b.z; r[7]=(__bf16)b.w;
  return r;
}

#define MFMA(A, B, C) __builtin_amdgcn_mfma_f32_16x16x32_bf16(A, B, C, 0, 0, 0)

// one GRU timestep; zrw/xhw are this step's prefetched inputs (refilled t+2)
__device__ __forceinline__ void gru_step4(
    int t, int w, int l, int g8, int m,
    const bf16x8 (*ufz)[4], const bf16x8 (*ufr)[4], const bf16x8 (*ufh)[4],
    __bf16* hx, __bf16* rhx,
    const unsigned int* xzr, const unsigned short* xh, float* out,
    const int* ub,
    unsigned int* zrw, unsigned short* xhw, float* h_own)
{
  const f32x4 zero = (f32x4){0.f, 0.f, 0.f, 0.f};
  const int tp = (t + 2 < T_LEN) ? t + 2 : T_LEN - 1;
  const bool wr = ((l & 1) == 0) & (l < 16);

  // ---- phase A: r gate only -> fastest path to rh exchange ----
  bf16x8 a0 = *reinterpret_cast<const bf16x8*>(&hx[      g8 * 8]);
  bf16x8 a1 = *reinterpret_cast<const bf16x8*>(&hx[32  + g8 * 8]);
  bf16x8 a2 = *reinterpret_cast<const bf16x8*>(&hx[64  + g8 * 8]);
  bf16x8 a3 = *reinterpret_cast<const bf16x8*>(&hx[96  + g8 * 8]);

  float rh[2], xzs[2];
  #pragma unroll
  for (int s = 0; s < 2; ++s){
    f32x4 r0 = MFMA(a0, ufr[s][0], zero);  r0 = MFMA(a1, ufr[s][1], r0);
    f32x4 r1 = MFMA(a2, ufr[s][2], zero);  r1 = MFMA(a3, ufr[s][3], r1);
    xzs[s] = bf2f((unsigned short)(zrw[s] & 0xffffu));   // save xz for phase B
    float r = sigm(bf2f((unsigned short)(zrw[s] >> 16)) + r0[0] + r1[0]);
    rh[s] = r * h_own[s];
  }
  float rhn0 = dpp_xor1(rh[0]);                          // all lanes (exec!)
  float rhn1 = dpp_xor1(rh[1]);
  if (wr){
    *reinterpret_cast<unsigned int*>(&rhx[w * 32      + (m & 14)]) = pack_bf16_rne(rh[0], rhn0);
    *reinterpret_cast<unsigned int*>(&rhx[w * 32 + 16 + (m & 14)]) = pack_bf16_rne(rh[1], rhn1);
  }
  BARRIER();                                             // rh visible

  // ---- phase B: z (register h frags, overlaps rh read) + h~ + update ----
  bf16x8 b0 = *reinterpret_cast<const bf16x8*>(&rhx[      g8 * 8]);
  bf16x8 b1 = *reinterpret_cast<const bf16x8*>(&rhx[32  + g8 * 8]);
  bf16x8 b2 = *reinterpret_cast<const bf16x8*>(&rhx[64  + g8 * 8]);
  bf16x8 b3 = *reinterpret_cast<const bf16x8*>(&rhx[96  + g8 * 8]);

  float hn[2];
  #pragma unroll
  for (int s = 0; s < 2; ++s){
    f32x4 z0 = MFMA(a0, ufz[s][0], zero);  z0 = MFMA(a1, ufz[s][1], z0);
    f32x4 z1 = MFMA(a2, ufz[s][2], zero);  z1 = MFMA(a3, ufz[s][3], z1);
    f32x4 h0 = MFMA(b0, ufh[s][0], zero);  h0 = MFMA(b1, ufh[s][1], h0);
    f32x4 h1 = MFMA(b2, ufh[s][2], zero);  h1 = MFMA(b3, ufh[s][3], h1);
    float z  = sigm(xzs[s] + z0[0] + z1[0]);
    float hc = tanh_fast(bf2f(xhw[s]) + h0[0] + h1[0]);
    hn[s] = h_own[s] + z * (hc - h_own[s]);              // (1-z)h + z*hc
    h_own[s] = hn[s];
  }
  float hnn0 = dpp_xor1(hn[0]);
  float hnn1 = dpp_xor1(hn[1]);
  if (wr){
    *reinterpret_cast<unsigned int*>(&hx[w * 32      + (m & 14)]) = pack_bf16_rne(hn[0], hnn0);
    *reinterpret_cast<unsigned int*>(&hx[w * 32 + 16 + (m & 14)]) = pack_bf16_rne(hn[1], hnn1);
  }
  if (l < 16){
    out[ub[0] + t * H_DIM] = hn[0];                      // fire-and-forget
    out[ub[1] + t * H_DIM] = hn[1];
  }
  #pragma unroll
  for (int s = 0; s < 2; ++s){                           // refill for t+2
    zrw[s] = xzr[ub[s] + tp * H_DIM];
    xhw[s] = xh [ub[s] + tp * H_DIM];
  }
  BARRIER();                                             // h' visible
}

__global__ __launch_bounds__(256, 1) void gru_rec4(
    const float* __restrict__ Uz, const float* __restrict__ Ur, const float* __restrict__ Uh,
    const int* __restrict__ lengths,
    const unsigned int* xzr,            // aliases `out` (packed bf16 xz|xr)
    const unsigned short* __restrict__ xh,
    float* out)
{
  __shared__ __align__(16) __bf16 hx[H_DIM];
  __shared__ __align__(16) __bf16 rhx[H_DIM];

  const int tid = threadIdx.x;
  const int w = tid >> 6, l = tid & 63;
  const int g8 = l >> 4;
  const int m  = l & 15;
  const int b  = blockIdx.x;
  const int len = lengths[b];

  // wave w owns units [32w, 32w+32): set s covers 32w+16s+m
  const int u0 = w * 32 + m;
  const int u1 = w * 32 + 16 + m;

  // U B-fragments: 2 sets x 3 gates x 4 k-steps x 4 VGPR = 96 VGPRs
  bf16x8 ufz[2][4], ufr[2][4], ufh[2][4];
  #pragma unroll
  for (int kk = 0; kk < 4; ++kk){
    const int ko = kk * 32 + g8 * 8;
    ufz[0][kk] = ld_u_frag(Uz + u0 * H_DIM + ko);
    ufr[0][kk] = ld_u_frag(Ur + u0 * H_DIM + ko);
    ufh[0][kk] = ld_u_frag(Uh + u0 * H_DIM + ko);
    ufz[1][kk] = ld_u_frag(Uz + u1 * H_DIM + ko);
    ufr[1][kk] = ld_u_frag(Ur + u1 * H_DIM + ko);
    ufh[1][kk] = ld_u_frag(Uh + u1 * H_DIM + ko);
  }

  if (tid < 64) reinterpret_cast<unsigned int*>(hx)[tid] = 0u;  // h0 = 0
  float h_own[2] = {0.f, 0.f};
  __syncthreads();

  const int ub[2] = { b * (T_LEN * H_DIM) + u0,
                      b * (T_LEN * H_DIM) + u1 };

  // 2-deep prefetch, named A/B register sets
  unsigned int  zrA[2], zrB[2];
  unsigned short xhA[2], xhB[2];
  #pragma unroll
  for (int s = 0; s < 2; ++s){
    zrA[s] = xzr[ub[s]];           xhA[s] = xh[ub[s]];
    zrB[s] = xzr[ub[s] + H_DIM];   xhB[s] = xh[ub[s] + H_DIM];
  }

  int t = 0;
  for (; t + 1 < len; t += 2){
    gru_step4(t,   w, l, g8, m, ufz, ufr, ufh, hx, rhx, xzr, xh, out, ub, zrA, xhA, h_own);
    gru_step4(t+1, w, l, g8, m, ufz, ufr, ufh, hx, rhx, xzr, xh, out, ub, zrB, xhB, h_own);
  }
  if (t < len){
    gru_step4(t,   w, l, g8, m, ufz, ufr, ufh, hx, rhx, xzr, xh, out, ub, zrA, xhA, h_own);
  }

  // masked region: exact zeros for t >= len (disjoint from h-stores)
  const long base = (long)b * (T_LEN * H_DIM);
  for (long i = (long)len * H_DIM + tid * 4; i < (long)T_LEN * H_DIM; i += 256 * 4){
    *reinterpret_cast<float4*>(out + base + i) = make_float4(0.f, 0.f, 0.f, 0.f);
  }
}

extern "C" void kernel_launch(void* const* d_in, const int* in_sizes, int n_in,
                              void* d_out, int out_size, void* d_ws, size_t ws_size,
                              hipStream_t stream){
  const float* x       = (const float*)d_in[0];
  const int*   lengths = (const int*)  d_in[1];
  const float* Wz = (const float*)d_in[2];
  const float* Uz = (const float*)d_in[3];
  const float* bz = (const float*)d_in[4];
  const float* Wr = (const float*)d_in[5];
  const float* Ur = (const float*)d_in[6];
  const float* br = (const float*)d_in[7];
  const float* Wh = (const float*)d_in[8];
  const float* Uh = (const float*)d_in[9];
  const float* bh = (const float*)d_in[10];

  unsigned int*   zr    = (unsigned int*)d_out;   // packed bf16 xz|xr, then h
  unsigned short* xhbuf = (unsigned short*)d_ws;  // bf16 xh

  gru_proj<<<dim3(2048), dim3(512), 0, stream>>>(x, Wz, Wr, Wh, bz, br, bh, zr, xhbuf);
  gru_rec4<<<dim3(128), dim3(256), 0, stream>>>(Uz, Ur, Uh, lengths, zr, xhbuf, (float*)d_out);
}

// Round 6
// 1233.648 us; speedup vs baseline: 1.4337x; 1.4337x over previous
//
#include <hip/hip_runtime.h>

// GRU: B=128, T=2048, H=128.
// Kernel 1 (gru_proj): xz/xr/xh = x @ W^T + b via bf16 MFMA 16x16x32.
//   xz,xr packed as 2x bf16 into d_out words (consumed then overwritten by h),
//   xh as bf16 into d_ws.
// Kernel 2 (gru_rec8): 1 batch/block x 128 blocks, 8 waves x 16 units (R4
//   config). Broadcast-A MFMA matvecs, 4 INDEPENDENT MFMAs per gate + scalar
//   add tree (one MFMA latency, not two). Phase A: r gate only -> shortest
//   path to rh exchange. Phase B: z on register-resident h frags (hides under
//   rh ds_read) + h~ + update. Fast rcp/exp2 hardware ops (no precise-div
//   sequence). 2 lgkm-only barriers/step; 2-deep global prefetch +
//   fire-and-forget h stores (vmcnt never drained in loop).

#define T_LEN 2048
#define H_DIM 128

typedef __attribute__((ext_vector_type(8))) __bf16 bf16x8;
typedef __attribute__((ext_vector_type(4))) float f32x4;

// raw barrier: drains LDS ops (cross-wave visibility) but NOT vmcnt. [m201]
#define BARRIER() asm volatile("s_waitcnt lgkmcnt(0)\n\ts_barrier" ::: "memory")

__device__ __forceinline__ unsigned short f2bf_bits(float f){
  __bf16 b = (__bf16)f;                     // fptrunc, RNE
  return __builtin_bit_cast(unsigned short, b);
}
__device__ __forceinline__ float bf2f(unsigned short s){
  unsigned int u = ((unsigned int)s) << 16;
  return __builtin_bit_cast(float, u);
}
__device__ __forceinline__ unsigned int pack_bf16_rne(float lo, float hi){
  return (unsigned int)f2bf_bits(lo) | (((unsigned int)f2bf_bits(hi)) << 16);
}
// hardware v_exp_f32 / v_rcp_f32 (avoid precise-division sequence)
__device__ __forceinline__ float sigm(float x){
  float e = __builtin_amdgcn_exp2f(-1.4426950408889634f * x);
  return __builtin_amdgcn_rcpf(1.0f + e);
}
__device__ __forceinline__ float tanh_fast(float x){
  float e = __builtin_amdgcn_exp2f(2.8853900817779268f * x);  // e^(2x)
  return 1.0f - 2.0f * __builtin_amdgcn_rcpf(e + 1.0f);       // inf-safe
}
// lane <- lane^1 value (quad_perm [1,0,3,2] = 0xB1); run in ALL lanes
__device__ __forceinline__ float dpp_xor1(float x){
  int r = __builtin_amdgcn_update_dpp(0, __builtin_bit_cast(int, x),
                                      0xB1, 0xF, 0xF, true);
  return __builtin_bit_cast(float, r);
}

// ---------------- projection GEMM (unchanged, verified) ----------------

__device__ __forceinline__ void stage_mat128(const float* __restrict__ src,
                                             __bf16 (*dst)[136], int tid){
  #pragma unroll
  for (int rep = 0; rep < 8; ++rep){
    int fi = rep * 2048 + tid * 4;
    float4 v = *reinterpret_cast<const float4*>(src + fi);
    int m = fi >> 7;
    int k = fi & 127;
    unsigned long long pk =
        (unsigned long long)f2bf_bits(v.x)
      | ((unsigned long long)f2bf_bits(v.y) << 16)
      | ((unsigned long long)f2bf_bits(v.z) << 32)
      | ((unsigned long long)f2bf_bits(v.w) << 48);
    *reinterpret_cast<unsigned long long*>(&dst[m][k]) = pk;
  }
}

__global__ __launch_bounds__(512, 2) void gru_proj(
    const float* __restrict__ x,
    const float* __restrict__ Wz, const float* __restrict__ Wr, const float* __restrict__ Wh,
    const float* __restrict__ bz, const float* __restrict__ br, const float* __restrict__ bh,
    unsigned int* __restrict__ out_zr, unsigned short* __restrict__ out_h)
{
  __shared__ __bf16 xs[128][136];
  __shared__ __bf16 wsh[3][128][136];

  const int tid = threadIdx.x;
  const long Mbase = (long)blockIdx.x * 128;

  stage_mat128(x + Mbase * H_DIM, xs, tid);
  stage_mat128(Wz, wsh[0], tid);
  stage_mat128(Wr, wsh[1], tid);
  stage_mat128(Wh, wsh[2], tid);
  __syncthreads();

  const int w  = tid >> 6, l = tid & 63;
  const int ml = l & 15;
  const int kl = (l >> 4) * 8;
  const int n  = w * 16 + ml;

  bf16x8 bfr[3][4];
  #pragma unroll
  for (int g = 0; g < 3; ++g)
    #pragma unroll
    for (int kk = 0; kk < 4; ++kk)
      bfr[g][kk] = *reinterpret_cast<const bf16x8*>(&wsh[g][n][kk * 32 + kl]);

  const float bzv = bz[n], brv = br[n], bhv = bh[n];

  f32x4 acc[8][3];
  #pragma unroll
  for (int mt = 0; mt < 8; ++mt)
    #pragma unroll
    for (int g = 0; g < 3; ++g)
      acc[mt][g] = (f32x4){0.f, 0.f, 0.f, 0.f};

  #pragma unroll
  for (int mt = 0; mt < 8; ++mt){
    #pragma unroll
    for (int kk = 0; kk < 4; ++kk){
      bf16x8 a = *reinterpret_cast<const bf16x8*>(&xs[mt * 16 + ml][kk * 32 + kl]);
      acc[mt][0] = __builtin_amdgcn_mfma_f32_16x16x32_bf16(a, bfr[0][kk], acc[mt][0], 0, 0, 0);
      acc[mt][1] = __builtin_amdgcn_mfma_f32_16x16x32_bf16(a, bfr[1][kk], acc[mt][1], 0, 0, 0);
      acc[mt][2] = __builtin_amdgcn_mfma_f32_16x16x32_bf16(a, bfr[2][kk], acc[mt][2], 0, 0, 0);
    }
  }

  #pragma unroll
  for (int mt = 0; mt < 8; ++mt){
    #pragma unroll
    for (int p = 0; p < 4; ++p){
      long row = Mbase + mt * 16 + (l >> 4) * 4 + p;
      float vz = acc[mt][0][p] + bzv;
      float vr = acc[mt][1][p] + brv;
      float vh = acc[mt][2][p] + bhv;
      unsigned int word = (unsigned int)f2bf_bits(vz)
                        | (((unsigned int)f2bf_bits(vr)) << 16);
      out_zr[row * H_DIM + n] = word;
      out_h [row * H_DIM + n] = f2bf_bits(vh);
    }
  }
}

// ---------------- recurrence: broadcast-A MFMA, 8 waves, 1 batch/block ------

__device__ __forceinline__ bf16x8 ld_u_frag(const float* p){
  float4 a = *reinterpret_cast<const float4*>(p);
  float4 b = *reinterpret_cast<const float4*>(p + 4);
  bf16x8 r;
  r[0]=(__bf16)a.x; r[1]=(__bf16)a.y; r[2]=(__bf16)a.z; r[3]=(__bf16)a.w;
  r[4]=(__bf16)b.x; r[5]=(__bf16)b.y; r[6]=(__bf16)b.z; r[7]=(__bf16)b.w;
  return r;
}

#define MFMA(A, B, C) __builtin_amdgcn_mfma_f32_16x16x32_bf16(A, B, C, 0, 0, 0)

__device__ __forceinline__ void gru_step8(
    int t, int ub, int g8, int l, int w,
    const bf16x8* ufz, const bf16x8* ufr, const bf16x8* ufh,
    __bf16* hx, __bf16* rhx,
    const unsigned int* xzr, const unsigned short* xh, float* out,
    unsigned int& zrw, unsigned short& xhw, float& h_own)
{
  const f32x4 zero = (f32x4){0.f, 0.f, 0.f, 0.f};
  const int tp = (t + 2 < T_LEN) ? t + 2 : T_LEN - 1;
  const bool wr = ((l & 1) == 0) & (l < 16);

  // ---- phase A: r gate only; 4 independent MFMAs + add tree ----
  bf16x8 a0 = *reinterpret_cast<const bf16x8*>(&hx[      g8 * 8]);
  bf16x8 a1 = *reinterpret_cast<const bf16x8*>(&hx[32  + g8 * 8]);
  bf16x8 a2 = *reinterpret_cast<const bf16x8*>(&hx[64  + g8 * 8]);
  bf16x8 a3 = *reinterpret_cast<const bf16x8*>(&hx[96  + g8 * 8]);
  f32x4 r0 = MFMA(a0, ufr[0], zero);
  f32x4 r1 = MFMA(a1, ufr[1], zero);
  f32x4 r2 = MFMA(a2, ufr[2], zero);
  f32x4 r3 = MFMA(a3, ufr[3], zero);

  float xzv = bf2f((unsigned short)(zrw & 0xffffu));   // keep for phase B
  float xrv = bf2f((unsigned short)(zrw >> 16));
  zrw = xzr[ub + tp * H_DIM];                           // refill for t+2

  float rg = sigm(xrv + ((r0[0] + r1[0]) + (r2[0] + r3[0])));
  float rh  = rg * h_own;
  float rhn = dpp_xor1(rh);                             // all lanes (exec!)
  if (wr)
    *reinterpret_cast<unsigned int*>(&rhx[w * 16 + (l & 14)]) = pack_bf16_rne(rh, rhn);
  BARRIER();                                            // rh visible

  // ---- phase B: z (register h frags; hides under rh read) + h~ + update ----
  bf16x8 b0 = *reinterpret_cast<const bf16x8*>(&rhx[      g8 * 8]);
  bf16x8 b1 = *reinterpret_cast<const bf16x8*>(&rhx[32  + g8 * 8]);
  bf16x8 b2 = *reinterpret_cast<const bf16x8*>(&rhx[64  + g8 * 8]);
  bf16x8 b3 = *reinterpret_cast<const bf16x8*>(&rhx[96  + g8 * 8]);
  f32x4 z0 = MFMA(a0, ufz[0], zero);
  f32x4 z1 = MFMA(a1, ufz[1], zero);
  f32x4 z2 = MFMA(a2, ufz[2], zero);
  f32x4 z3 = MFMA(a3, ufz[3], zero);
  f32x4 h0 = MFMA(b0, ufh[0], zero);
  f32x4 h1 = MFMA(b1, ufh[1], zero);
  f32x4 h2 = MFMA(b2, ufh[2], zero);
  f32x4 h3 = MFMA(b3, ufh[3], zero);

  float zg = sigm(xzv + ((z0[0] + z1[0]) + (z2[0] + z3[0])));
  float hc = tanh_fast(bf2f(xhw) + ((h0[0] + h1[0]) + (h2[0] + h3[0])));
  float hn = fmaf(zg, hc - h_own, h_own);               // (1-z)h + z*hc
  h_own = hn;
  float hnn = dpp_xor1(hn);
  if (wr)
    *reinterpret_cast<unsigned int*>(&hx[w * 16 + (l & 14)]) = pack_bf16_rne(hn, hnn);
  if (l < 16)
    out[ub + t * H_DIM] = hn;                           // fire-and-forget
  xhw = xh[ub + tp * H_DIM];                            // refill for t+2
  BARRIER();                                            // h' visible
}

__global__ __launch_bounds__(512, 1) void gru_rec8(
    const float* __restrict__ Uz, const float* __restrict__ Ur, const float* __restrict__ Uh,
    const int* __restrict__ lengths,
    const unsigned int* xzr,            // aliases `out` (packed bf16 xz|xr)
    const unsigned short* __restrict__ xh,
    float* out)
{
  __shared__ __align__(16) __bf16 hx[H_DIM];
  __shared__ __align__(16) __bf16 rhx[H_DIM];

  const int tid = threadIdx.x;
  const int w = tid >> 6, l = tid & 63;
  const int g8 = l >> 4;                // k-slice within each 32-k block
  const int u  = w * 16 + (l & 15);     // owned unit (C col)
  const int b  = blockIdx.x;
  const int len = lengths[b];

  // U B-fragments: 3 gates x 4 k-steps x 4 VGPR = 48 VGPRs
  bf16x8 ufz[4], ufr[4], ufh[4];
  #pragma unroll
  for (int kk = 0; kk < 4; ++kk){
    const int ko = kk * 32 + g8 * 8;
    ufz[kk] = ld_u_frag(Uz + u * H_DIM + ko);
    ufr[kk] = ld_u_frag(Ur + u * H_DIM + ko);
    ufh[kk] = ld_u_frag(Uh + u * H_DIM + ko);
  }

  if (tid < 64) reinterpret_cast<unsigned int*>(hx)[tid] = 0u;  // h0 = 0
  float h_own = 0.f;
  __syncthreads();

  const int ub = b * (T_LEN * H_DIM) + u;   // element offset of (b, t=0, u)

  // 2-deep prefetch, named regs
  unsigned int  zrA, zrB;
  unsigned short xhA, xhB;
  zrA = xzr[ub];             xhA = xh[ub];
  zrB = xzr[ub + H_DIM];     xhB = xh[ub + H_DIM];

  int t = 0;
  for (; t + 1 < len; t += 2){
    gru_step8(t,   ub, g8, l, w, ufz, ufr, ufh, hx, rhx, xzr, xh, out, zrA, xhA, h_own);
    gru_step8(t+1, ub, g8, l, w, ufz, ufr, ufh, hx, rhx, xzr, xh, out, zrB, xhB, h_own);
  }
  if (t < len){
    gru_step8(t,   ub, g8, l, w, ufz, ufr, ufh, hx, rhx, xzr, xh, out, zrA, xhA, h_own);
  }

  // masked region: exact zeros for t >= len (disjoint from h-stores)
  const long base = (long)b * (T_LEN * H_DIM);
  for (long i = (long)len * H_DIM + tid * 4; i < (long)T_LEN * H_DIM; i += 512 * 4){
    *reinterpret_cast<float4*>(out + base + i) = make_float4(0.f, 0.f, 0.f, 0.f);
  }
}

extern "C" void kernel_launch(void* const* d_in, const int* in_sizes, int n_in,
                              void* d_out, int out_size, void* d_ws, size_t ws_size,
                              hipStream_t stream){
  const float* x       = (const float*)d_in[0];
  const int*   lengths = (const int*)  d_in[1];
  const float* Wz = (const float*)d_in[2];
  const float* Uz = (const float*)d_in[3];
  const float* bz = (const float*)d_in[4];
  const float* Wr = (const float*)d_in[5];
  const float* Ur = (const float*)d_in[6];
  const float* br = (const float*)d_in[7];
  const float* Wh = (const float*)d_in[8];
  const float* Uh = (const float*)d_in[9];
  const float* bh = (const float*)d_in[10];

  unsigned int*   zr    = (unsigned int*)d_out;   // packed bf16 xz|xr, then h
  unsigned short* xhbuf = (unsigned short*)d_ws;  // bf16 xh

  gru_proj<<<dim3(2048), dim3(512), 0, stream>>>(x, Wz, Wr, Wh, bz, br, bh, zr, xhbuf);
  gru_rec8<<<dim3(128), dim3(512), 0, stream>>>(Uz, Ur, Uh, lengths, zr, xhbuf, (float*)d_out);
}